// Round 6
// baseline (526.344 us; speedup 1.0000x reference)
//
#include <hip/hip_runtime.h>

#define IMG 1024
#define BH  8    // output rows per band; 128 bands x 16 images = 2048 wgs = 8/CU

// Barrier-free, LDS-free Perona-Malik iteration (Round-4 structure, BH=8).
// Each lane owns 4 output cols and redundantly computes a 6-wide flux window
// from an 8-wide input window, so no cross-lane exchange is needed. Vertical
// neighbors ride register ring-buffers; 1-row load lookahead.
__global__ __launch_bounds__(256, 8)
void pm_sweep(const float* __restrict__ in, float* __restrict__ out) {
    const int tid = threadIdx.x;
    const int c0  = tid << 2;                       // 0..1020
    const int y0  = blockIdx.x * BH;
    const size_t base = (size_t)blockIdx.y << 20;   // * IMG*IMG
    const float* I = in + base;
    float*       O = out + base;

    const bool le = (c0 == 0);          // image left edge lane
    const bool re = (c0 == IMG - 4);    // image right edge lane
    const int aC = le ? 0 : c0 - 2;     // 8B-aligned, in-bounds
    const int bC = re ? IMG - 4 : c0 + 2;

    // register pipelines: input rows (8 wide), flux rows (6 wide x 2 comps)
    float r0[8], r1[8], r2[8];
    float f1x[6], f1y[6], f2x[6], f2y[6];
    #pragma unroll
    for (int j = 0; j < 8; ++j) { r0[j] = 0.f; r1[j] = 0.f; r2[j] = 0.f; }
    #pragma unroll
    for (int j = 0; j < 6; ++j) { f1x[j] = 0.f; f1y[j] = 0.f; f2x[j] = 0.f; f2y[j] = 0.f; }

    float4 A = make_float4(0.f, 0.f, 0.f, 0.f), B = A;
    if (y0 >= 2) {  // prologue: row y0-2 (only band 0 skips)
        const size_t r = (size_t)(y0 - 2) << 10;
        A = *(const float4*)(I + r + aC);
        B = *(const float4*)(I + r + bC);
    }

    #pragma unroll
    for (int k = 0; k < BH + 4; ++k) {
        const int yld = y0 - 2 + k;

        // ---- commit pending load into the input ring (8-wide window) ----
        #pragma unroll
        for (int j = 0; j < 8; ++j) { r2[j] = r1[j]; r1[j] = r0[j]; }
        r0[0] = le ? 0.f : A.x;  r0[1] = le ? 0.f : A.y;
        r0[2] = le ? A.x : A.z;  r0[3] = le ? A.y : A.w;
        r0[4] = re ? B.z : B.x;  r0[5] = re ? B.w : B.y;
        r0[6] = re ? 0.f : B.z;  r0[7] = re ? 0.f : B.w;

        // ---- issue next row's load (wave-uniform branch) ----
        if (k < BH + 3) {
            const int row = yld + 1;
            if (row >= 0 && row < IMG) {
                const size_t r = (size_t)row << 10;
                A = *(const float4*)(I + r + aC);
                B = *(const float4*)(I + r + bC);
            } else { A = make_float4(0.f, 0.f, 0.f, 0.f); B = A; }
        }

        // ---- flux row yf = yld-1 on 6-wide window (cols c0-1..c0+4) ----
        float fNx[6], fNy[6];
        const int yf = yld - 1;
        if (yf >= 0 && yf < IMG) {
            float s[8], d[8];
            #pragma unroll
            for (int j = 0; j < 8; ++j) {
                s[j] = fmaf(2.f, r1[j], r2[j] + r0[j]);   // col sums   (x8 scale)
                d[j] = r0[j] - r2[j];                     // row diffs
            }
            #pragma unroll
            for (int i = 0; i < 6; ++i) {
                const float GX  = s[i+2] - s[i];                     // 8*grad_x
                const float GY  = fmaf(2.f, d[i+1], d[i] + d[i+2]);  // 8*grad_y
                const float m2  = fmaf(GY, GY, GX * GX);
                const float mag = fmaf(m2, 0.015625f, 1e-8f);        // gx^2+gy^2+eps
                const float den = fmaf(mag, 400.f, 1.f);             // 1 + mag/kappa^2
                const float c   = __builtin_amdgcn_rcpf(den);
                fNx[i] = c * GX;                                     // 8*flux_x
                fNy[i] = c * GY;                                     // 8*flux_y
            }
            // flux is zero-padded by the second conv: kill cols -1 / 1024
            if (le) { fNx[0] = 0.f; fNy[0] = 0.f; }
            if (re) { fNx[5] = 0.f; fNy[5] = 0.f; }
        } else {
            #pragma unroll
            for (int i = 0; i < 6; ++i) { fNx[i] = 0.f; fNy[i] = 0.f; }
        }

        // ---- divergence + Euler update, row yd = yld-2 (f2,f1,fN = yd-1,yd,yd+1) ----
        if (k >= 4) {
            float S[6], D[6];
            #pragma unroll
            for (int j = 0; j < 6; ++j) {
                S[j] = fmaf(2.f, f1x[j], f2x[j] + fNx[j]);
                D[j] = fNy[j] - f2y[j];
            }
            float o[4];
            #pragma unroll
            for (int i = 0; i < 4; ++i) {
                const float DX = S[i+2] - S[i];
                const float DY = fmaf(2.f, D[i+1], D[i] + D[i+2]);
                o[i] = fmaf(DX + DY, 0.00390625f, r2[i+2]);   // in + 0.25*div/64
            }
            const int yd = yld - 2;
            *(float4*)(O + ((size_t)yd << 10) + c0) = make_float4(o[0], o[1], o[2], o[3]);
        }

        // ---- shift flux ring (renamed away by full unroll) ----
        #pragma unroll
        for (int j = 0; j < 6; ++j) {
            f2x[j] = f1x[j]; f2y[j] = f1y[j];
            f1x[j] = fNx[j]; f1y[j] = fNy[j];
        }
    }
}

extern "C" void kernel_launch(void* const* d_in, const int* in_sizes, int n_in,
                              void* d_out, int out_size, void* d_ws, size_t ws_size,
                              hipStream_t stream) {
    const float* img = (const float*)d_in[0];
    float* out = (float*)d_out;
    float* ws  = (float*)d_ws;
    const int N = in_sizes[0] / (IMG * IMG);

    dim3 grid(IMG / BH, N);
    dim3 block(256);
    pm_sweep<<<grid, block, 0, stream>>>(img, out);
    pm_sweep<<<grid, block, 0, stream>>>(out, ws);
    pm_sweep<<<grid, block, 0, stream>>>(ws, out);
}

// Round 7
// 169.554 us; speedup vs baseline: 3.1043x; 3.1043x over previous
//
#include <hip/hip_runtime.h>

#define IMG 1024
#define BH  8    // output rows per band; 128 bands x 16 images = 2048 wgs = 8/CU

// Barrier-free, LDS-free Perona-Malik iteration (Round-4 structure, BH=8).
// NOTE: launch_bounds min-waves stays 4 — forcing 8 caps VGPR at 32 and
// spills the register pipelines (R6: 450 MB scratch traffic, 4x slower).
// Natural allocation is 56 VGPR <= 64, so 8 blocks/CU still fit at runtime.
__global__ __launch_bounds__(256, 4)
void pm_sweep(const float* __restrict__ in, float* __restrict__ out) {
    const int tid = threadIdx.x;
    const int c0  = tid << 2;                       // 0..1020
    const int y0  = blockIdx.x * BH;
    const size_t base = (size_t)blockIdx.y << 20;   // * IMG*IMG
    const float* I = in + base;
    float*       O = out + base;

    const bool le = (c0 == 0);          // image left edge lane
    const bool re = (c0 == IMG - 4);    // image right edge lane
    const int aC = le ? 0 : c0 - 2;     // 8B-aligned, in-bounds
    const int bC = re ? IMG - 4 : c0 + 2;

    // register pipelines: input rows (8 wide), flux rows (6 wide x 2 comps)
    float r0[8], r1[8], r2[8];
    float f1x[6], f1y[6], f2x[6], f2y[6];
    #pragma unroll
    for (int j = 0; j < 8; ++j) { r0[j] = 0.f; r1[j] = 0.f; r2[j] = 0.f; }
    #pragma unroll
    for (int j = 0; j < 6; ++j) { f1x[j] = 0.f; f1y[j] = 0.f; f2x[j] = 0.f; f2y[j] = 0.f; }

    float4 A = make_float4(0.f, 0.f, 0.f, 0.f), B = A;
    if (y0 >= 2) {  // prologue: row y0-2 (only band 0 skips)
        const size_t r = (size_t)(y0 - 2) << 10;
        A = *(const float4*)(I + r + aC);
        B = *(const float4*)(I + r + bC);
    }

    #pragma unroll
    for (int k = 0; k < BH + 4; ++k) {
        const int yld = y0 - 2 + k;

        // ---- commit pending load into the input ring (8-wide window) ----
        #pragma unroll
        for (int j = 0; j < 8; ++j) { r2[j] = r1[j]; r1[j] = r0[j]; }
        r0[0] = le ? 0.f : A.x;  r0[1] = le ? 0.f : A.y;
        r0[2] = le ? A.x : A.z;  r0[3] = le ? A.y : A.w;
        r0[4] = re ? B.z : B.x;  r0[5] = re ? B.w : B.y;
        r0[6] = re ? 0.f : B.z;  r0[7] = re ? 0.f : B.w;

        // ---- issue next row's load (wave-uniform branch) ----
        if (k < BH + 3) {
            const int row = yld + 1;
            if (row >= 0 && row < IMG) {
                const size_t r = (size_t)row << 10;
                A = *(const float4*)(I + r + aC);
                B = *(const float4*)(I + r + bC);
            } else { A = make_float4(0.f, 0.f, 0.f, 0.f); B = A; }
        }

        // ---- flux row yf = yld-1 on 6-wide window (cols c0-1..c0+4) ----
        float fNx[6], fNy[6];
        const int yf = yld - 1;
        if (yf >= 0 && yf < IMG) {
            float s[8], d[8];
            #pragma unroll
            for (int j = 0; j < 8; ++j) {
                s[j] = fmaf(2.f, r1[j], r2[j] + r0[j]);   // col sums   (x8 scale)
                d[j] = r0[j] - r2[j];                     // row diffs
            }
            #pragma unroll
            for (int i = 0; i < 6; ++i) {
                const float GX  = s[i+2] - s[i];                     // 8*grad_x
                const float GY  = fmaf(2.f, d[i+1], d[i] + d[i+2]);  // 8*grad_y
                const float m2  = fmaf(GY, GY, GX * GX);
                const float mag = fmaf(m2, 0.015625f, 1e-8f);        // gx^2+gy^2+eps
                const float den = fmaf(mag, 400.f, 1.f);             // 1 + mag/kappa^2
                const float c   = __builtin_amdgcn_rcpf(den);
                fNx[i] = c * GX;                                     // 8*flux_x
                fNy[i] = c * GY;                                     // 8*flux_y
            }
            // flux is zero-padded by the second conv: kill cols -1 / 1024
            if (le) { fNx[0] = 0.f; fNy[0] = 0.f; }
            if (re) { fNx[5] = 0.f; fNy[5] = 0.f; }
        } else {
            #pragma unroll
            for (int i = 0; i < 6; ++i) { fNx[i] = 0.f; fNy[i] = 0.f; }
        }

        // ---- divergence + Euler update, row yd = yld-2 (f2,f1,fN = yd-1,yd,yd+1) ----
        if (k >= 4) {
            float S[6], D[6];
            #pragma unroll
            for (int j = 0; j < 6; ++j) {
                S[j] = fmaf(2.f, f1x[j], f2x[j] + fNx[j]);
                D[j] = fNy[j] - f2y[j];
            }
            float o[4];
            #pragma unroll
            for (int i = 0; i < 4; ++i) {
                const float DX = S[i+2] - S[i];
                const float DY = fmaf(2.f, D[i+1], D[i] + D[i+2]);
                o[i] = fmaf(DX + DY, 0.00390625f, r2[i+2]);   // in + 0.25*div/64
            }
            const int yd = yld - 2;
            *(float4*)(O + ((size_t)yd << 10) + c0) = make_float4(o[0], o[1], o[2], o[3]);
        }

        // ---- shift flux ring (renamed away by full unroll) ----
        #pragma unroll
        for (int j = 0; j < 6; ++j) {
            f2x[j] = f1x[j]; f2y[j] = f1y[j];
            f1x[j] = fNx[j]; f1y[j] = fNy[j];
        }
    }
}

extern "C" void kernel_launch(void* const* d_in, const int* in_sizes, int n_in,
                              void* d_out, int out_size, void* d_ws, size_t ws_size,
                              hipStream_t stream) {
    const float* img = (const float*)d_in[0];
    float* out = (float*)d_out;
    float* ws  = (float*)d_ws;
    const int N = in_sizes[0] / (IMG * IMG);

    dim3 grid(IMG / BH, N);
    dim3 block(256);
    pm_sweep<<<grid, block, 0, stream>>>(img, out);
    pm_sweep<<<grid, block, 0, stream>>>(out, ws);
    pm_sweep<<<grid, block, 0, stream>>>(ws, out);
}